// Round 24
// baseline (310.352 us; speedup 1.0000x reference)
//
#include <hip/hip_runtime.h>
#include <hip/hip_bf16.h>

#define NB 2
#define SEQ 2048
#define DMODEL 2048
#define NH 16
#define HD 128
// SM_SCALE * log2(e): softmax computed in exp2 domain
#define QSCALE (0.08838834764831845f * 1.44269504088896f)
#define THRL2 11.5f

using bf16x8 = __attribute__((ext_vector_type(8))) __bf16;
using f32x4  = __attribute__((ext_vector_type(4))) float;

#define MFMA16 __builtin_amdgcn_mfma_f32_16x16x32_bf16

typedef __attribute__((address_space(1))) const void* gptr_t;
typedef __attribute__((address_space(3))) void* lptr_t;

__device__ inline void gload_lds16(const unsigned short* g, unsigned short* l) {
    __builtin_amdgcn_global_load_lds((gptr_t)g, (lptr_t)l, 16, 0, 0);
}

__device__ inline unsigned short f2b(float f) {
    unsigned u = __builtin_bit_cast(unsigned, f);
    u += 0x7FFF + ((u >> 16) & 1);
    return (unsigned short)(u >> 16);
}
__device__ inline float b2f(unsigned short h) {
    return __builtin_bit_cast(float, (unsigned)h << 16);
}
__device__ inline float fexp2(float x) {
    float r;
    asm("v_exp_f32 %0, %1" : "=v"(r) : "v"(x));
    return r;
}
__device__ inline unsigned cvtpk(float a, float b) {   // low=bf16(a), high=bf16(b)
    unsigned r;
    asm("v_cvt_pk_bf16_f32 %0, %1, %2" : "=v"(r) : "v"(a), "v"(b));
    return r;
}

// ---------------- fused: all 4 casts + RoPE table, one launch ----------------
__global__ void cast_all(const float* __restrict__ x, const float* __restrict__ wqk,
                         const float* __restrict__ wv, const float* __restrict__ wo,
                         unsigned short* __restrict__ xb, unsigned short* __restrict__ wb,
                         float2* __restrict__ tab) {
    int idx = blockIdx.x * 256 + threadIdx.x;
    if (idx < 6291456) {
        const float* src; unsigned short* dst; int off;
        if (idx < 2097152)      { src = x;   dst = xb;             off = 0; }
        else if (idx < 4194304) { src = wqk; dst = wb;             off = 2097152; }
        else if (idx < 5242880) { src = wv;  dst = wb + 8388608;   off = 4194304; }
        else                    { src = wo;  dst = wb + 12582912;  off = 5242880; }
        int i = (idx - off) * 4;
        float4 v = *reinterpret_cast<const float4*>(src + i);
        ushort4 o;
        o.x = f2b(v.x); o.y = f2b(v.y); o.z = f2b(v.z); o.w = f2b(v.w);
        *reinterpret_cast<ushort4*>(dst + i) = o;
    } else {
        int k = idx - 6291456;              // 0..131071 = 2048 x 64
        int i = k & 63;
        int s = k >> 6;
        float inv = exp2f(-13.287712379549449f * (float)i * (1.0f / 64.0f));
        float ang = (float)s * inv;
        float sn, cs;
        sincosf(ang, &sn, &cs);
        tab[k] = make_float2(cs, sn);
    }
}

// ======== GEMM 128x256 2-phase core (r13/r19-verified: 0 conflicts, counted vmcnt) ========
// MODE 0: fp32 C write. MODE 2: fused QKV epilogue (bx<8 Q-rope->qb, 8..15 K-rope->kb,
// 16..23 V transposed directly -> vt[bh][d][s]). Q/K stores pair-packed (even lanes
// compute both rotated halves from the RoPE shuffle and do one u32 store).
template<int MODE>
__global__ __launch_bounds__(512) void gemm8p(const unsigned short* __restrict__ A,
                                              const unsigned short* __restrict__ Bw,
                                              void* __restrict__ Cout,
                                              unsigned short* __restrict__ qb,
                                              unsigned short* __restrict__ kbp,
                                              unsigned short* __restrict__ vt,
                                              const float2* __restrict__ tab,
                                              int M, int N, int K) {
    __shared__ __align__(16) char lds[98304];   // [A0 16K][B0 32K][A1 16K][B1 32K]
    int tid = threadIdx.x;
    int lane = tid & 63;
    int wid = tid >> 6;
    int wm = wid >> 2, wn = wid & 3;
    int row0 = blockIdx.y * 128;
    int col0 = blockIdx.x * 256;
    int lr = lane & 15, g = lane >> 4;

    const unsigned short* srcA[2];
    const unsigned short* srcB[4];
#pragma unroll
    for (int i = 0; i < 2; i++) {
        int chunk = i * 512 + tid;
        int ksub = chunk >> 9;
        int cw = chunk & 511;
        int row = cw >> 2, c = cw & 3;
        int cs = c ^ ((row >> 1) & 3);
        srcA[i] = A + (size_t)(row0 + row) * K + ksub * 32 + cs * 8;
    }
#pragma unroll
    for (int i = 0; i < 4; i++) {
        int chunk = i * 512 + tid;
        int ksub = chunk >> 10;
        int cw = chunk & 1023;
        int row = cw >> 2, c = cw & 3;
        int cs = c ^ ((row >> 1) & 3);
        srcB[i] = Bw + (size_t)(col0 + row) * K + ksub * 32 + cs * 8;
    }

    int offA[4][2], offB[4][2];
#pragma unroll
    for (int i = 0; i < 4; i++) {
        int row = wm * 64 + i * 16 + lr;
#pragma unroll
        for (int ks = 0; ks < 2; ks++)
            offA[i][ks] = ks * 8192 + row * 64 + ((g ^ ((row >> 1) & 3)) * 16);
    }
#pragma unroll
    for (int j = 0; j < 4; j++) {
        int row = wn * 64 + j * 16 + lr;
#pragma unroll
        for (int ks = 0; ks < 2; ks++)
            offB[j][ks] = ks * 16384 + row * 64 + ((g ^ ((row >> 1) & 3)) * 16);
    }

    f32x4 acc[4][4] = {};
    int NT = K >> 6;

#define STAGE8(t) {                                                                   \
        int kb_ = (t) * 64;                                                           \
        int bs_ = ((t) & 1) * 49152;                                                  \
        _Pragma("unroll")                                                             \
        for (int i_ = 0; i_ < 2; i_++)                                                \
            gload_lds16(srcA[i_] + kb_,                                               \
                (unsigned short*)(lds + bs_ + (i_ * 512 + (tid & ~63)) * 16));        \
        _Pragma("unroll")                                                             \
        for (int i_ = 0; i_ < 4; i_++)                                                \
            gload_lds16(srcB[i_] + kb_,                                               \
                (unsigned short*)(lds + bs_ + 16384 + (i_ * 512 + (tid & ~63)) * 16)); \
    }

    STAGE8(0);
    for (int t = 0; t < NT; ++t) {
        if (t + 1 < NT) {
            STAGE8(t + 1);
            asm volatile("s_waitcnt vmcnt(6)" ::: "memory");
        } else {
            asm volatile("s_waitcnt vmcnt(0)" ::: "memory");
        }
        __builtin_amdgcn_s_barrier();
        __builtin_amdgcn_sched_barrier(0);

        const char* ab = lds + (t & 1) * 49152;
        const char* bb = ab + 16384;

        bf16x8 b[4][2], a[2][2];
#pragma unroll
        for (int j = 0; j < 4; j++)
#pragma unroll
            for (int ks = 0; ks < 2; ks++)
                b[j][ks] = *reinterpret_cast<const bf16x8*>(bb + offB[j][ks]);
#pragma unroll
        for (int i = 0; i < 2; i++)
#pragma unroll
            for (int ks = 0; ks < 2; ks++)
                a[i][ks] = *reinterpret_cast<const bf16x8*>(ab + offA[i][ks]);
        asm volatile("s_waitcnt lgkmcnt(0)" ::: "memory");
        __builtin_amdgcn_sched_barrier(0);
        __builtin_amdgcn_s_setprio(1);
#pragma unroll
        for (int ks = 0; ks < 2; ks++)
#pragma unroll
            for (int i = 0; i < 2; i++)
#pragma unroll
                for (int j = 0; j < 4; j++)
                    acc[i][j] = MFMA16(a[i][ks], b[j][ks], acc[i][j], 0, 0, 0);
        __builtin_amdgcn_s_setprio(0);

        bf16x8 a2[2][2];
#pragma unroll
        for (int i = 0; i < 2; i++)
#pragma unroll
            for (int ks = 0; ks < 2; ks++)
                a2[i][ks] = *reinterpret_cast<const bf16x8*>(ab + offA[2 + i][ks]);
        asm volatile("s_waitcnt lgkmcnt(0)" ::: "memory");
        __builtin_amdgcn_sched_barrier(0);
        __builtin_amdgcn_s_barrier();
        __builtin_amdgcn_sched_barrier(0);
        __builtin_amdgcn_s_setprio(1);
#pragma unroll
        for (int ks = 0; ks < 2; ks++)
#pragma unroll
            for (int i = 0; i < 2; i++)
#pragma unroll
                for (int j = 0; j < 4; j++)
                    acc[2 + i][j] = MFMA16(a2[i][ks], b[j][ks], acc[2 + i][j], 0, 0, 0);
        __builtin_amdgcn_s_setprio(0);
    }
#undef STAGE8

    int orow = g * 4;
    if (MODE == 0) {
#pragma unroll
        for (int i = 0; i < 4; i++) {
#pragma unroll
            for (int j = 0; j < 4; j++) {
                int r0 = row0 + wm * 64 + i * 16 + orow;
                int c  = col0 + wn * 64 + j * 16 + lr;
#pragma unroll
                for (int r = 0; r < 4; r++)
                    ((float*)Cout)[(size_t)(r0 + r) * N + c] = acc[i][j][r];
            }
        }
    } else {
        int bx = blockIdx.x;
        if (bx < 16) {
            const bool isQ = (bx < 8);
            unsigned short* dst = isQ ? qb : kbp;
            bool evenlane = ((lr & 1) == 0);
#pragma unroll
            for (int i = 0; i < 4; i++) {
#pragma unroll
                for (int j = 0; j < 4; j++) {
                    int c = col0 + wn * 64 + j * 16 + lr;
                    int cc = c & 2047;
                    int h = cc >> 7, d = cc & 127, i2 = d >> 1;
#pragma unroll
                    for (int r = 0; r < 4; r++) {
                        int trow = row0 + wm * 64 + i * 16 + orow + r;
                        int s = trow & (SEQ - 1), bb2 = trow >> 11;
                        float v = acc[i][j][r];
                        float pv = __shfl_xor(v, 1);          // all lanes execute
                        if (evenlane) {
                            // even lane holds xe = v, xo = pv; computes both outputs
                            float2 cssn = tab[s * 64 + i2];
                            float oe = v * cssn.x - pv * cssn.y;
                            float oo = v * cssn.y + pv * cssn.x;
                            if (isQ) { oe *= QSCALE; oo *= QSCALE; }
                            unsigned pk = (unsigned)f2b(oe) | ((unsigned)f2b(oo) << 16);
                            *reinterpret_cast<unsigned*>(
                                dst + ((size_t)((bb2 * NH + h) * SEQ + s)) * HD + d) = pk;
                        }
                    }
                }
            }
        } else {
            // V: write transposed directly into vt[bh][d][s] (8B stores over r-dim = s)
#pragma unroll
            for (int i = 0; i < 4; i++) {
#pragma unroll
                for (int j = 0; j < 4; j++) {
                    int cc = col0 + wn * 64 + j * 16 + lr - 4096;
                    int h = cc >> 7, d = cc & 127;
                    int trow0 = row0 + wm * 64 + i * 16 + orow;
                    int s0 = trow0 & (SEQ - 1), bb2 = trow0 >> 11;
                    int bh = bb2 * NH + h;
                    ushort4 o4;
                    o4.x = f2b(acc[i][j][0]);
                    o4.y = f2b(acc[i][j][1]);
                    o4.z = f2b(acc[i][j][2]);
                    o4.w = f2b(acc[i][j][3]);
                    *reinterpret_cast<ushort4*>(vt + ((size_t)bh * HD + d) * SEQ + s0) = o4;
                }
            }
        }
    }
}

// ---------------- flash attention v10 (r23-verified, unchanged) ----------------
__global__ __launch_bounds__(64, 2) void attn10(const unsigned short* __restrict__ Q,
                                                const unsigned short* __restrict__ Kb,
                                                const unsigned short* __restrict__ Vt,
                                                unsigned short* __restrict__ O) {
    __shared__ __align__(16) char lds[20480];   // K 16K | P 4K

    int lane = threadIdx.x;
    int bid = blockIdx.x;
    int qt = 63 - (bid >> 5);       // heavy blocks first
    int bh = bid & 31;              // XCD head affinity
    int q0 = qt * 32;
    int ktiles = (qt >> 1) + 1;     // KVBLK=64 tiles covering 0..q0+31
    int lr = lane & 15;
    int g  = lane >> 4;
    int g4 = g * 4;
    int lk = g * 8;

    const unsigned short* Qp = Q  + (size_t)bh * SEQ * HD;
    const unsigned short* Kp = Kb + (size_t)bh * SEQ * HD;
    const unsigned short* Vp = Vt + (size_t)bh * HD * SEQ;
    char* pl = lds + 16384;
    int b = bh >> 4;
    int h = bh & 15;

    int srcoff[16];
#pragma unroll
    for (int i2 = 0; i2 < 16; ++i2) {
        int r = i2 * 4 + g;                     // rows 0..63
        srcoff[i2] = r * HD + ((lr ^ (r & 7)) * 8);
    }

#define STAGEK64(kvbase)                                                            \
    {                                                                               \
        const unsigned short* kbase = Kp + (size_t)(kvbase) * HD;                   \
        _Pragma("unroll")                                                           \
        for (int i2 = 0; i2 < 16; ++i2)                                             \
            gload_lds16(kbase + srcoff[i2],                                         \
                        (unsigned short*)(lds + i2 * 1024));                        \
    }

    bf16x8 qf[2][4];
#pragma unroll
    for (int f = 0; f < 2; f++)
#pragma unroll
        for (int kb = 0; kb < 4; kb++)
            qf[f][kb] = *reinterpret_cast<const bf16x8*>(Qp + (size_t)(q0 + f * 16 + lr) * HD + kb * 32 + lk);

    f32x4 oacc[2][8] = {};
    float m[2] = { -1e30f, -1e30f }, l[2] = { 0.0f, 0.0f };
    int qrow[2] = { q0 + lr, q0 + 16 + lr };

    STAGEK64(0);

    for (int t = 0; t < ktiles; ++t) {
        int kv0 = t * 64;
        asm volatile("s_waitcnt vmcnt(0)" ::: "memory");   // K tile landed (staged last trip)
        __builtin_amdgcn_sched_barrier(0);

        // ---- QK^T swapped: lane owns q = lane&15, 16 in-lane kv scores ----
        f32x4 s[2][4] = {};
#pragma unroll
        for (int kb = 0; kb < 4; kb++) {
#pragma unroll
            for (int jj = 0; jj < 4; jj++) {
                int row = jj * 16 + lr;
                int cin = ((kb * 4 + g) ^ (row & 7));
                bf16x8 kf = *reinterpret_cast<const bf16x8*>(lds + row * 256 + cin * 16);
                s[0][jj] = MFMA16(kf, qf[0][kb], s[0][jj], 0, 0, 0);
                s[1][jj] = MFMA16(kf, qf[1][kb], s[1][jj], 0, 0, 0);
            }
        }

        // ---- V prefetch (issue early, consumed at PV) ----
        bf16x8 vf[8][2];
#pragma unroll
        for (int db = 0; db < 8; db++)
#pragma unroll
            for (int ks = 0; ks < 2; ks++)
                vf[db][ks] = *reinterpret_cast<const bf16x8*>(Vp + (size_t)(db * 16 + lr) * SEQ + kv0 + ks * 32 + lk);

        // ---- in-lane online softmax (exp2 domain, defer-max) ----
#pragma unroll
        for (int f = 0; f < 2; f++) {
            int q = qrow[f];
            bool full = (kv0 + 63 <= q0 + f * 16);   // wave-uniform
            float mx = -1e30f;
            if (full) {
#pragma unroll
                for (int jj = 0; jj < 4; jj++)
#pragma unroll
                    for (int r = 0; r < 4; r++)
                        mx = fmaxf(mx, s[f][jj][r]);
            } else {
#pragma unroll
                for (int jj = 0; jj < 4; jj++)
#pragma unroll
                    for (int r = 0; r < 4; r++) {
                        int kv = kv0 + jj * 16 + g4 + r;
                        float v = (kv <= q) ? s[f][jj][r] : -1e30f;
                        s[f][jj][r] = v;
                        mx = fmaxf(mx, v);
                    }
            }
            mx = fmaxf(mx, __shfl_xor(mx, 16));
            mx = fmaxf(mx, __shfl_xor(mx, 32));

            if (!__all(mx <= m[f] + THRL2)) {
                float sc = fexp2(m[f] - fmaxf(m[f], mx));
                float mn = fmaxf(m[f], mx);
                m[f] = mn;
                l[f] *= sc;
#pragma unroll
                for (int db = 0; db < 8; db++)
#pragma unroll
                    for (int r = 0; r < 4; r++)
                        oacc[f][db][r] *= sc;
            }

            int row = f * 16 + lr;
            int rb = row * 128;                 // 128B per P row (64 kv x bf16)
            int sw = (row & 7) << 4;
            float rs = 0.0f;
#pragma unroll
            for (int jj = 0; jj < 4; jj++)
#pragma unroll
                for (int hh = 0; hh < 2; hh++) {
                    float p0 = fexp2(s[f][jj][2 * hh]     - m[f]);
                    float p1 = fexp2(s[f][jj][2 * hh + 1] - m[f]);
                    rs += p0 + p1;
                    unsigned pk = cvtpk(p0, p1);
                    int colb = jj * 32 + g * 8 + 4 * hh;
                    *reinterpret_cast<unsigned*>(pl + rb + (colb ^ sw)) = pk;
                }
            rs += __shfl_xor(rs, 16);
            rs += __shfl_xor(rs, 32);
            l[f] += rs;
        }

        asm volatile("s_waitcnt lgkmcnt(0)" ::: "memory");  // QK ds_reads + P writes retired
        __builtin_amdgcn_sched_barrier(0);

        // stage NEXT tile into the same K buffer (WAR-safe: reads drained above);
        // lands under PV + sibling wave; waited at next trip's vmcnt(0).
        if (t + 1 < ktiles) STAGEK64(kv0 + 64);

        // ---- P fragments + swapped PV ----
        bf16x8 pb[2][2];
#pragma unroll
        for (int f = 0; f < 2; f++)
#pragma unroll
            for (int ks = 0; ks < 2; ks++) {
                int row = f * 16 + lr;
                int off = row * 128 + ((ks * 64 + g * 16) ^ ((row & 7) << 4));
                pb[f][ks] = *reinterpret_cast<const bf16x8*>(pl + off);
            }
#pragma unroll
        for (int db = 0; db < 8; db++)
#pragma unroll
            for (int ks = 0; ks < 2; ks++) {
                oacc[0][db] = MFMA16(vf[db][ks], pb[0][ks], oacc[0][db], 0, 0, 0);
                oacc[1][db] = MFMA16(vf[db][ks], pb[1][ks], oacc[1][db], 0, 0, 0);
            }
    }

#pragma unroll
    for (int f = 0; f < 2; f++) {
        float inv = 1.0f / l[f];
        int q = q0 + f * 16 + lr;
        unsigned short* op = O + ((size_t)(b * SEQ + q)) * DMODEL + h * HD;
#pragma unroll
        for (int db = 0; db < 8; db++) {
            ushort4 o4;
            o4.x = f2b(oacc[f][db][0] * inv);
            o4.y = f2b(oacc[f][db][1] * inv);
            o4.z = f2b(oacc[f][db][2] * inv);
            o4.w = f2b(oacc[f][db][3] * inv);
            *reinterpret_cast<ushort4*>(op + db * 16 + g4) = o4;
        }
    }
#undef STAGEK64
}

extern "C" void kernel_launch(void* const* d_in, const int* in_sizes, int n_in,
                              void* d_out, int out_size, void* d_ws, size_t ws_size,
                              hipStream_t stream) {
    const float* x   = (const float*)d_in[0];
    const float* wqk = (const float*)d_in[1];
    const float* wv  = (const float*)d_in[2];
    const float* wo  = (const float*)d_in[3];

    unsigned short* xb  = (unsigned short*)d_ws;            // [4096][2048]
    unsigned short* wb  = xb  + (size_t)8388608;            // [8192][2048]: wqk | wv | wo
    unsigned short* qb  = wb  + (size_t)16777216;           // [B][H][S][HD]
    unsigned short* kb  = qb  + (size_t)8388608;
    unsigned short* vt  = kb  + (size_t)8388608;            // [B][H][HD][S]
    unsigned short* ao  = vt  + (size_t)8388608;            // [4096][2048]
    float2* tab = (float2*)(ao + (size_t)8388608);          // [2048][64]

    cast_all<<<25088, 256, 0, stream>>>(x, wqk, wv, wo, xb, wb, tab);

    // fused QKV projection + RoPE + V-transpose epilogue (768 blocks = 3 exact CU rounds)
    gemm8p<2><<<dim3(24, 32), 512, 0, stream>>>(xb, wb, nullptr, qb, kb, vt, tab, 4096, 6144, 2048);

    attn10<<<2048, 64, 0, stream>>>(qb, kb, vt, ao);

    // out projection (256 blocks = 1 exact CU round)
    gemm8p<0><<<dim3(8, 32), 512, 0, stream>>>(ao, wb + 12582912, d_out, nullptr, nullptr, nullptr, nullptr, 4096, 2048, 2048);
}

// Round 25
// 270.746 us; speedup vs baseline: 1.1463x; 1.1463x over previous
//
#include <hip/hip_runtime.h>
#include <hip/hip_bf16.h>

#define NB 2
#define SEQ 2048
#define DMODEL 2048
#define NH 16
#define HD 128
// SM_SCALE * log2(e): softmax computed in exp2 domain
#define QSCALE (0.08838834764831845f * 1.44269504088896f)
#define THRL2 11.5f

using bf16x8 = __attribute__((ext_vector_type(8))) __bf16;
using f32x4  = __attribute__((ext_vector_type(4))) float;

#define MFMA16 __builtin_amdgcn_mfma_f32_16x16x32_bf16

typedef __attribute__((address_space(1))) const void* gptr_t;
typedef __attribute__((address_space(3))) void* lptr_t;

__device__ inline void gload_lds16(const unsigned short* g, unsigned short* l) {
    __builtin_amdgcn_global_load_lds((gptr_t)g, (lptr_t)l, 16, 0, 0);
}

__device__ inline unsigned short f2b(float f) {
    unsigned u = __builtin_bit_cast(unsigned, f);
    u += 0x7FFF + ((u >> 16) & 1);
    return (unsigned short)(u >> 16);
}
__device__ inline float b2f(unsigned short h) {
    return __builtin_bit_cast(float, (unsigned)h << 16);
}
__device__ inline float fexp2(float x) {
    float r;
    asm("v_exp_f32 %0, %1" : "=v"(r) : "v"(x));
    return r;
}
__device__ inline unsigned cvtpk(float a, float b) {   // low=bf16(a), high=bf16(b)
    unsigned r;
    asm("v_cvt_pk_bf16_f32 %0, %1, %2" : "=v"(r) : "v"(a), "v"(b));
    return r;
}

// ---------------- fused: all 4 casts + RoPE table, one launch ----------------
__global__ void cast_all(const float* __restrict__ x, const float* __restrict__ wqk,
                         const float* __restrict__ wv, const float* __restrict__ wo,
                         unsigned short* __restrict__ xb, unsigned short* __restrict__ wb,
                         float2* __restrict__ tab) {
    int idx = blockIdx.x * 256 + threadIdx.x;
    if (idx < 6291456) {
        const float* src; unsigned short* dst; int off;
        if (idx < 2097152)      { src = x;   dst = xb;             off = 0; }
        else if (idx < 4194304) { src = wqk; dst = wb;             off = 2097152; }
        else if (idx < 5242880) { src = wv;  dst = wb + 8388608;   off = 4194304; }
        else                    { src = wo;  dst = wb + 12582912;  off = 5242880; }
        int i = (idx - off) * 4;
        float4 v = *reinterpret_cast<const float4*>(src + i);
        ushort4 o;
        o.x = f2b(v.x); o.y = f2b(v.y); o.z = f2b(v.z); o.w = f2b(v.w);
        *reinterpret_cast<ushort4*>(dst + i) = o;
    } else {
        int k = idx - 6291456;              // 0..131071 = 2048 x 64
        int i = k & 63;
        int s = k >> 6;
        float inv = exp2f(-13.287712379549449f * (float)i * (1.0f / 64.0f));
        float ang = (float)s * inv;
        float sn, cs;
        sincosf(ang, &sn, &cs);
        tab[k] = make_float2(cs, sn);
    }
}

// ======== GEMM 128x256 2-phase core (r13/r19-verified: 0 conflicts, counted vmcnt) ========
// MODE 0: fp32 C write. MODE 2: fused QKV epilogue (bx<8 Q-rope->qb, 8..15 K-rope->kb,
// 16..23 V transposed directly -> vt[bh][d][s]).
template<int MODE>
__global__ __launch_bounds__(512) void gemm8p(const unsigned short* __restrict__ A,
                                              const unsigned short* __restrict__ Bw,
                                              void* __restrict__ Cout,
                                              unsigned short* __restrict__ qb,
                                              unsigned short* __restrict__ kbp,
                                              unsigned short* __restrict__ vt,
                                              const float2* __restrict__ tab,
                                              int M, int N, int K) {
    __shared__ __align__(16) char lds[98304];   // [A0 16K][B0 32K][A1 16K][B1 32K]
    int tid = threadIdx.x;
    int lane = tid & 63;
    int wid = tid >> 6;
    int wm = wid >> 2, wn = wid & 3;
    int row0 = blockIdx.y * 128;
    int col0 = blockIdx.x * 256;
    int lr = lane & 15, g = lane >> 4;

    const unsigned short* srcA[2];
    const unsigned short* srcB[4];
#pragma unroll
    for (int i = 0; i < 2; i++) {
        int chunk = i * 512 + tid;
        int ksub = chunk >> 9;
        int cw = chunk & 511;
        int row = cw >> 2, c = cw & 3;
        int cs = c ^ ((row >> 1) & 3);
        srcA[i] = A + (size_t)(row0 + row) * K + ksub * 32 + cs * 8;
    }
#pragma unroll
    for (int i = 0; i < 4; i++) {
        int chunk = i * 512 + tid;
        int ksub = chunk >> 10;
        int cw = chunk & 1023;
        int row = cw >> 2, c = cw & 3;
        int cs = c ^ ((row >> 1) & 3);
        srcB[i] = Bw + (size_t)(col0 + row) * K + ksub * 32 + cs * 8;
    }

    int offA[4][2], offB[4][2];
#pragma unroll
    for (int i = 0; i < 4; i++) {
        int row = wm * 64 + i * 16 + lr;
#pragma unroll
        for (int ks = 0; ks < 2; ks++)
            offA[i][ks] = ks * 8192 + row * 64 + ((g ^ ((row >> 1) & 3)) * 16);
    }
#pragma unroll
    for (int j = 0; j < 4; j++) {
        int row = wn * 64 + j * 16 + lr;
#pragma unroll
        for (int ks = 0; ks < 2; ks++)
            offB[j][ks] = ks * 16384 + row * 64 + ((g ^ ((row >> 1) & 3)) * 16);
    }

    f32x4 acc[4][4] = {};
    int NT = K >> 6;

#define STAGE8(t) {                                                                   \
        int kb_ = (t) * 64;                                                           \
        int bs_ = ((t) & 1) * 49152;                                                  \
        _Pragma("unroll")                                                             \
        for (int i_ = 0; i_ < 2; i_++)                                                \
            gload_lds16(srcA[i_] + kb_,                                               \
                (unsigned short*)(lds + bs_ + (i_ * 512 + (tid & ~63)) * 16));        \
        _Pragma("unroll")                                                             \
        for (int i_ = 0; i_ < 4; i_++)                                                \
            gload_lds16(srcB[i_] + kb_,                                               \
                (unsigned short*)(lds + bs_ + 16384 + (i_ * 512 + (tid & ~63)) * 16)); \
    }

    STAGE8(0);
    for (int t = 0; t < NT; ++t) {
        if (t + 1 < NT) {
            STAGE8(t + 1);
            asm volatile("s_waitcnt vmcnt(6)" ::: "memory");
        } else {
            asm volatile("s_waitcnt vmcnt(0)" ::: "memory");
        }
        __builtin_amdgcn_s_barrier();
        __builtin_amdgcn_sched_barrier(0);

        const char* ab = lds + (t & 1) * 49152;
        const char* bb = ab + 16384;

        bf16x8 b[4][2], a[2][2];
#pragma unroll
        for (int j = 0; j < 4; j++)
#pragma unroll
            for (int ks = 0; ks < 2; ks++)
                b[j][ks] = *reinterpret_cast<const bf16x8*>(bb + offB[j][ks]);
#pragma unroll
        for (int i = 0; i < 2; i++)
#pragma unroll
            for (int ks = 0; ks < 2; ks++)
                a[i][ks] = *reinterpret_cast<const bf16x8*>(ab + offA[i][ks]);
        asm volatile("s_waitcnt lgkmcnt(0)" ::: "memory");
        __builtin_amdgcn_sched_barrier(0);
        __builtin_amdgcn_s_setprio(1);
#pragma unroll
        for (int ks = 0; ks < 2; ks++)
#pragma unroll
            for (int i = 0; i < 2; i++)
#pragma unroll
                for (int j = 0; j < 4; j++)
                    acc[i][j] = MFMA16(a[i][ks], b[j][ks], acc[i][j], 0, 0, 0);
        __builtin_amdgcn_s_setprio(0);

        bf16x8 a2[2][2];
#pragma unroll
        for (int i = 0; i < 2; i++)
#pragma unroll
            for (int ks = 0; ks < 2; ks++)
                a2[i][ks] = *reinterpret_cast<const bf16x8*>(ab + offA[2 + i][ks]);
        asm volatile("s_waitcnt lgkmcnt(0)" ::: "memory");
        __builtin_amdgcn_sched_barrier(0);
        __builtin_amdgcn_s_barrier();
        __builtin_amdgcn_sched_barrier(0);
        __builtin_amdgcn_s_setprio(1);
#pragma unroll
        for (int ks = 0; ks < 2; ks++)
#pragma unroll
            for (int i = 0; i < 2; i++)
#pragma unroll
                for (int j = 0; j < 4; j++)
                    acc[2 + i][j] = MFMA16(a2[i][ks], b[j][ks], acc[2 + i][j], 0, 0, 0);
        __builtin_amdgcn_s_setprio(0);
    }
#undef STAGE8

    int orow = g * 4;
    if (MODE == 0) {
#pragma unroll
        for (int i = 0; i < 4; i++) {
#pragma unroll
            for (int j = 0; j < 4; j++) {
                int r0 = row0 + wm * 64 + i * 16 + orow;
                int c  = col0 + wn * 64 + j * 16 + lr;
#pragma unroll
                for (int r = 0; r < 4; r++)
                    ((float*)Cout)[(size_t)(r0 + r) * N + c] = acc[i][j][r];
            }
        }
    } else {
        int bx = blockIdx.x;
        if (bx < 16) {
            const bool isQ = (bx < 8);
            unsigned short* dst = isQ ? qb : kbp;
#pragma unroll
            for (int i = 0; i < 4; i++) {
#pragma unroll
                for (int j = 0; j < 4; j++) {
                    int c = col0 + wn * 64 + j * 16 + lr;
                    int cc = c & 2047;
                    int h = cc >> 7, d = cc & 127, i2 = d >> 1;
                    int odd = lr & 1;
#pragma unroll
                    for (int r = 0; r < 4; r++) {
                        int trow = row0 + wm * 64 + i * 16 + orow + r;
                        int s = trow & (SEQ - 1), bb2 = trow >> 11;
                        float v = acc[i][j][r];
                        float pv = __shfl_xor(v, 1);
                        float2 cssn = tab[s * 64 + i2];
                        float out = odd ? (pv * cssn.y + v * cssn.x)
                                        : (v * cssn.x - pv * cssn.y);
                        if (isQ) out *= QSCALE;
                        dst[((size_t)((bb2 * NH + h) * SEQ + s)) * HD + d] = f2b(out);
                    }
                }
            }
        } else {
            // V: write transposed directly into vt[bh][d][s] (8B stores over r-dim = s)
#pragma unroll
            for (int i = 0; i < 4; i++) {
#pragma unroll
                for (int j = 0; j < 4; j++) {
                    int cc = col0 + wn * 64 + j * 16 + lr - 4096;
                    int h = cc >> 7, d = cc & 127;
                    int trow0 = row0 + wm * 64 + i * 16 + orow;
                    int s0 = trow0 & (SEQ - 1), bb2 = trow0 >> 11;
                    int bh = bb2 * NH + h;
                    ushort4 o4;
                    o4.x = f2b(acc[i][j][0]);
                    o4.y = f2b(acc[i][j][1]);
                    o4.z = f2b(acc[i][j][2]);
                    o4.w = f2b(acc[i][j][3]);
                    *reinterpret_cast<ushort4*>(vt + ((size_t)bh * HD + d) * SEQ + s0) = o4;
                }
            }
        }
    }
}

// ---------------- flash attention v10: KVBLK=64, single K buffer, 2 waves/SIMD ----------------
// QK/softmax/P-layout/PV = attn6 (r13-verified, KVBLK=64); staging = single-buffer
// issue-after-lgkm-drain; launch_bounds(64,2) keeps VGPR cap 256. LDS 16K K + 4K P
// -> 8 blocks/CU, 2 waves/SIMD. 2048 blocks, qt descending, bh XCD affinity.
__global__ __launch_bounds__(64, 2) void attn10(const unsigned short* __restrict__ Q,
                                                const unsigned short* __restrict__ Kb,
                                                const unsigned short* __restrict__ Vt,
                                                unsigned short* __restrict__ O) {
    __shared__ __align__(16) char lds[20480];   // K 16K | P 4K

    int lane = threadIdx.x;
    int bid = blockIdx.x;
    int qt = 63 - (bid >> 5);       // heavy blocks first
    int bh = bid & 31;              // XCD head affinity
    int q0 = qt * 32;
    int ktiles = (qt >> 1) + 1;     // KVBLK=64 tiles covering 0..q0+31
    int lr = lane & 15;
    int g  = lane >> 4;
    int g4 = g * 4;
    int lk = g * 8;

    const unsigned short* Qp = Q  + (size_t)bh * SEQ * HD;
    const unsigned short* Kp = Kb + (size_t)bh * SEQ * HD;
    const unsigned short* Vp = Vt + (size_t)bh * HD * SEQ;
    char* pl = lds + 16384;
    int b = bh >> 4;
    int h = bh & 15;

    int srcoff[16];
#pragma unroll
    for (int i2 = 0; i2 < 16; ++i2) {
        int r = i2 * 4 + g;                     // rows 0..63
        srcoff[i2] = r * HD + ((lr ^ (r & 7)) * 8);
    }

#define STAGEK64(kvbase)                                                            \
    {                                                                               \
        const unsigned short* kbase = Kp + (size_t)(kvbase) * HD;                   \
        _Pragma("unroll")                                                           \
        for (int i2 = 0; i2 < 16; ++i2)                                             \
            gload_lds16(kbase + srcoff[i2],                                         \
                        (unsigned short*)(lds + i2 * 1024));                        \
    }

    bf16x8 qf[2][4];
#pragma unroll
    for (int f = 0; f < 2; f++)
#pragma unroll
        for (int kb = 0; kb < 4; kb++)
            qf[f][kb] = *reinterpret_cast<const bf16x8*>(Qp + (size_t)(q0 + f * 16 + lr) * HD + kb * 32 + lk);

    f32x4 oacc[2][8] = {};
    float m[2] = { -1e30f, -1e30f }, l[2] = { 0.0f, 0.0f };
    int qrow[2] = { q0 + lr, q0 + 16 + lr };

    STAGEK64(0);

    for (int t = 0; t < ktiles; ++t) {
        int kv0 = t * 64;
        asm volatile("s_waitcnt vmcnt(0)" ::: "memory");   // K tile landed (staged last trip)
        __builtin_amdgcn_sched_barrier(0);

        // ---- QK^T swapped: lane owns q = lane&15, 16 in-lane kv scores ----
        f32x4 s[2][4] = {};
#pragma unroll
        for (int kb = 0; kb < 4; kb++) {
#pragma unroll
            for (int jj = 0; jj < 4; jj++) {
                int row = jj * 16 + lr;
                int cin = ((kb * 4 + g) ^ (row & 7));
                bf16x8 kf = *reinterpret_cast<const bf16x8*>(lds + row * 256 + cin * 16);
                s[0][jj] = MFMA16(kf, qf[0][kb], s[0][jj], 0, 0, 0);
                s[1][jj] = MFMA16(kf, qf[1][kb], s[1][jj], 0, 0, 0);
            }
        }

        // ---- V prefetch (issue early, consumed at PV) ----
        bf16x8 vf[8][2];
#pragma unroll
        for (int db = 0; db < 8; db++)
#pragma unroll
            for (int ks = 0; ks < 2; ks++)
                vf[db][ks] = *reinterpret_cast<const bf16x8*>(Vp + (size_t)(db * 16 + lr) * SEQ + kv0 + ks * 32 + lk);

        // ---- in-lane online softmax (exp2 domain, defer-max) ----
#pragma unroll
        for (int f = 0; f < 2; f++) {
            int q = qrow[f];
            bool full = (kv0 + 63 <= q0 + f * 16);   // wave-uniform
            float mx = -1e30f;
            if (full) {
#pragma unroll
                for (int jj = 0; jj < 4; jj++)
#pragma unroll
                    for (int r = 0; r < 4; r++)
                        mx = fmaxf(mx, s[f][jj][r]);
            } else {
#pragma unroll
                for (int jj = 0; jj < 4; jj++)
#pragma unroll
                    for (int r = 0; r < 4; r++) {
                        int kv = kv0 + jj * 16 + g4 + r;
                        float v = (kv <= q) ? s[f][jj][r] : -1e30f;
                        s[f][jj][r] = v;
                        mx = fmaxf(mx, v);
                    }
            }
            mx = fmaxf(mx, __shfl_xor(mx, 16));
            mx = fmaxf(mx, __shfl_xor(mx, 32));

            if (!__all(mx <= m[f] + THRL2)) {
                float mn = fmaxf(m[f], mx);
                float sc = fexp2(m[f] - mn);
                m[f] = mn;
                l[f] *= sc;
#pragma unroll
                for (int db = 0; db < 8; db++)
#pragma unroll
                    for (int r = 0; r < 4; r++)
                        oacc[f][db][r] *= sc;
            }

            int row = f * 16 + lr;
            int rb = row * 128;                 // 128B per P row (64 kv x bf16)
            int sw = (row & 7) << 4;
            float rs = 0.0f;
#pragma unroll
            for (int jj = 0; jj < 4; jj++)
#pragma unroll
                for (int hh = 0; hh < 2; hh++) {
                    float p0 = fexp2(s[f][jj][2 * hh]     - m[f]);
                    float p1 = fexp2(s[f][jj][2 * hh + 1] - m[f]);
                    rs += p0 + p1;
                    unsigned pk = cvtpk(p0, p1);
                    int colb = jj * 32 + g * 8 + 4 * hh;
                    *reinterpret_cast<unsigned*>(pl + rb + (colb ^ sw)) = pk;
                }
            rs += __shfl_xor(rs, 16);
            rs += __shfl_xor(rs, 32);
            l[f] += rs;
        }

        asm volatile("s_waitcnt lgkmcnt(0)" ::: "memory");  // QK ds_reads + P writes retired
        __builtin_amdgcn_sched_barrier(0);

        // stage NEXT tile into the same K buffer (WAR-safe: reads drained above);
        // lands under PV + sibling wave; waited at next trip's vmcnt(0).
        if (t + 1 < ktiles) STAGEK64(kv0 + 64);

        // ---- P fragments + swapped PV ----
        bf16x8 pb[2][2];
#pragma unroll
        for (int f = 0; f < 2; f++)
#pragma unroll
            for (int ks = 0; ks < 2; ks++) {
                int row = f * 16 + lr;
                int off = row * 128 + ((ks * 64 + g * 16) ^ ((row & 7) << 4));
                pb[f][ks] = *reinterpret_cast<const bf16x8*>(pl + off);
            }
#pragma unroll
        for (int db = 0; db < 8; db++)
#pragma unroll
            for (int ks = 0; ks < 2; ks++) {
                oacc[0][db] = MFMA16(vf[db][ks], pb[0][ks], oacc[0][db], 0, 0, 0);
                oacc[1][db] = MFMA16(vf[db][ks], pb[1][ks], oacc[1][db], 0, 0, 0);
            }
    }

#pragma unroll
    for (int f = 0; f < 2; f++) {
        float inv = 1.0f / l[f];
        int q = q0 + f * 16 + lr;
        unsigned short* op = O + ((size_t)(b * SEQ + q)) * DMODEL + h * HD;
#pragma unroll
        for (int db = 0; db < 8; db++) {
            ushort4 o4;
            o4.x = f2b(oacc[f][db][0] * inv);
            o4.y = f2b(oacc[f][db][1] * inv);
            o4.z = f2b(oacc[f][db][2] * inv);
            o4.w = f2b(oacc[f][db][3] * inv);
            *reinterpret_cast<ushort4*>(op + db * 16 + g4) = o4;
        }
    }
#undef STAGEK64
}

extern "C" void kernel_launch(void* const* d_in, const int* in_sizes, int n_in,
                              void* d_out, int out_size, void* d_ws, size_t ws_size,
                              hipStream_t stream) {
    const float* x   = (const float*)d_in[0];
    const float* wqk = (const float*)d_in[1];
    const float* wv  = (const float*)d_in[2];
    const float* wo  = (const float*)d_in[3];

    unsigned short* xb  = (unsigned short*)d_ws;            // [4096][2048]
    unsigned short* wb  = xb  + (size_t)8388608;            // [8192][2048]: wqk | wv | wo
    unsigned short* qb  = wb  + (size_t)16777216;           // [B][H][S][HD]
    unsigned short* kb  = qb  + (size_t)8388608;
    unsigned short* vt  = kb  + (size_t)8388608;            // [B][H][HD][S]
    unsigned short* ao  = vt  + (size_t)8388608;            // [4096][2048]
    float2* tab = (float2*)(ao + (size_t)8388608);          // [2048][64]

    cast_all<<<25088, 256, 0, stream>>>(x, wqk, wv, wo, xb, wb, tab);

    // fused QKV projection + RoPE + V-transpose epilogue (768 blocks = 3 exact CU rounds)
    gemm8p<2><<<dim3(24, 32), 512, 0, stream>>>(xb, wb, nullptr, qb, kb, vt, tab, 4096, 6144, 2048);

    attn10<<<2048, 64, 0, stream>>>(qb, kb, vt, ao);

    // out projection (256 blocks = 1 exact CU round)
    gemm8p<0><<<dim3(8, 32), 512, 0, stream>>>(ao, wb + 12582912, d_out, nullptr, nullptr, nullptr, nullptr, 4096, 2048, 2048);
}